// Round 1
// baseline (31817.923 us; speedup 1.0000x reference)
//
#include <hip/hip_runtime.h>

typedef unsigned short ushort_t;
typedef short sh8 __attribute__((ext_vector_type(8)));     // 8 bf16 (4 VGPR)
typedef float f32x4 __attribute__((ext_vector_type(4)));   // 4 fp32 acc

#define MFMA16(a,b,c) __builtin_amdgcn_mfma_f32_16x16x32_bf16((a),(b),(c),0,0,0)

#define SEQL   512
#define BATCH  64
#define HDIM   1024
#define G3     3072
#define AROWS  (SEQL*BATCH)          // 32768
#define YSZ    (SEQL*BATCH*HDIM)     // 33554432

__device__ __forceinline__ ushort_t f2bf(float x) {
  unsigned u = __float_as_uint(x);
  u += 0x7FFFu + ((u >> 16) & 1u);    // RNE
  return (ushort_t)(u >> 16);
}
__device__ __forceinline__ float bf2f(ushort_t h) {
  return __uint_as_float(((unsigned)h) << 16);
}

// ---------------- conversion / init ----------------
__global__ void cvt_kernel(const float* __restrict__ wih, const float* __restrict__ whh,
                           const float* __restrict__ h0,
                           ushort_t* __restrict__ WihH, ushort_t* __restrict__ WihL,
                           ushort_t* __restrict__ WhhH, ushort_t* __restrict__ WhhL,
                           float* __restrict__ hf, ushort_t* __restrict__ hH,
                           ushort_t* __restrict__ hL) {
  const int NW = G3 * HDIM;
  int i0 = blockIdx.x * blockDim.x + threadIdx.x;
  int stride = gridDim.x * blockDim.x;
  for (int i = i0; i < NW; i += stride) {
    float x = wih[i]; ushort_t h = f2bf(x);
    WihH[i] = h; WihL[i] = f2bf(x - bf2f(h));
    float y = whh[i]; ushort_t g = f2bf(y);
    WhhH[i] = g; WhhL[i] = f2bf(y - bf2f(g));
  }
  for (int i = i0; i < BATCH * HDIM; i += stride) {
    float x = h0[i]; hf[i] = x;
    ushort_t h = f2bf(x); hH[i] = h; hL[i] = f2bf(x - bf2f(h));
  }
}

// ---------------- phase 1: gx = input @ W_ih^T + b_ih ----------------
// tile 128(M) x 128(N), 4 waves, wave = 32 rows x 128 cols; A fp32->hi/lo on the fly.
__global__ __launch_bounds__(256) void gemm_gx(
    const float* __restrict__ A,            // [32768][1024] fp32
    const ushort_t* __restrict__ BH, const ushort_t* __restrict__ BL, // [3072][1024]
    const float* __restrict__ bias,         // [3072]
    float* __restrict__ gx)                 // [32768][3072]
{
  int bid = blockIdx.x;
  int mt = bid / 24, nt = bid % 24;
  int w = threadIdx.x >> 6, l = threadIdx.x & 63;
  int lr = l & 15, lk = (l >> 4) * 8;

  f32x4 acc[2][8];
  #pragma unroll
  for (int mi = 0; mi < 2; ++mi)
    #pragma unroll
    for (int ni = 0; ni < 8; ++ni) acc[mi][ni] = (f32x4){0.f, 0.f, 0.f, 0.f};

  int arow0 = mt * 128 + w * 32 + lr;
  int brow0 = nt * 128 + lr;

  for (int k0 = 0; k0 < HDIM; k0 += 32) {
    int ka = k0 + lk;
    sh8 aH[2], aL[2];
    #pragma unroll
    for (int mi = 0; mi < 2; ++mi) {
      const float* ap = A + (size_t)(arow0 + mi * 16) * HDIM + ka;
      float4 x0 = *(const float4*)ap;
      float4 x1 = *(const float4*)(ap + 4);
      float xs[8] = {x0.x, x0.y, x0.z, x0.w, x1.x, x1.y, x1.z, x1.w};
      #pragma unroll
      for (int j = 0; j < 8; ++j) {
        ushort_t h = f2bf(xs[j]);
        aH[mi][j] = (short)h;
        aL[mi][j] = (short)f2bf(xs[j] - bf2f(h));
      }
    }
    #pragma unroll
    for (int ni = 0; ni < 8; ++ni) {
      const ushort_t* bh = BH + (size_t)(brow0 + ni * 16) * HDIM + ka;
      const ushort_t* bl = BL + (size_t)(brow0 + ni * 16) * HDIM + ka;
      sh8 bHf = *(const sh8*)bh;
      sh8 bLf = *(const sh8*)bl;
      #pragma unroll
      for (int mi = 0; mi < 2; ++mi) {
        acc[mi][ni] = MFMA16(aH[mi], bHf, acc[mi][ni]);
        acc[mi][ni] = MFMA16(aH[mi], bLf, acc[mi][ni]);
        acc[mi][ni] = MFMA16(aL[mi], bHf, acc[mi][ni]);
      }
    }
  }
  int rb = (l >> 4) * 4;
  #pragma unroll
  for (int mi = 0; mi < 2; ++mi)
    #pragma unroll
    for (int ni = 0; ni < 8; ++ni) {
      int col = nt * 128 + ni * 16 + lr;
      float b = bias[col];
      #pragma unroll
      for (int j = 0; j < 4; ++j) {
        int row = mt * 128 + w * 32 + mi * 16 + rb + j;
        gx[(size_t)row * G3 + col] = acc[mi][ni][j] + b;
      }
    }
}

// ---------------- device-scope barrier ----------------
__device__ __forceinline__ void gbar(unsigned* cnt, unsigned target) {
  __syncthreads();
  if (threadIdx.x == 0) {
    __hip_atomic_fetch_add(cnt, 1u, __ATOMIC_RELEASE, __HIP_MEMORY_SCOPE_AGENT);
    while (__hip_atomic_load(cnt, __ATOMIC_ACQUIRE, __HIP_MEMORY_SCOPE_AGENT) < target)
      __builtin_amdgcn_s_sleep(1);
  }
  __syncthreads();
}

// ---------------- phase 2: persistent recurrence ----------------
// 64 WGs x 256 threads. WG g owns hidden cols [16g,16g+16). Wave w owns rows [16w,16w+16).
__global__ __launch_bounds__(256) void gru_rec(
    const float* __restrict__ gx,                 // [512][64][3072]
    const ushort_t* __restrict__ WhhH, const ushort_t* __restrict__ WhhL, // [3072][1024]
    const float* __restrict__ bias_hh,            // [3072]
    float* __restrict__ hf,                       // [2][64][1024] fp32
    ushort_t* __restrict__ hH, ushort_t* __restrict__ hL,   // [2][64][1024]
    ushort_t* __restrict__ rhH, ushort_t* __restrict__ rhL, // [64][1024]
    float* __restrict__ Y, float* __restrict__ Yh,
    unsigned* __restrict__ cnt)
{
  int g = blockIdx.x;
  int w = threadIdx.x >> 6, l = threadIdx.x & 63;
  int lr = l & 15, lk = (l >> 4) * 8, rb = (l >> 4) * 4;
  int c0 = g * 16;
  int m0 = w * 16;
  unsigned bar = 0;

  const ushort_t* wrH = WhhH + (size_t)(c0 + lr) * HDIM;
  const ushort_t* wrL = WhhL + (size_t)(c0 + lr) * HDIM;
  const ushort_t* wzH = WhhH + (size_t)(1024 + c0 + lr) * HDIM;
  const ushort_t* wzL = WhhL + (size_t)(1024 + c0 + lr) * HDIM;
  const ushort_t* wnH = WhhH + (size_t)(2048 + c0 + lr) * HDIM;
  const ushort_t* wnL = WhhL + (size_t)(2048 + c0 + lr) * HDIM;

  for (int t = 0; t < SEQL; ++t) {
    int par = t & 1;
    const ushort_t* ha = hH + par * (BATCH * HDIM) + (m0 + lr) * HDIM;
    const ushort_t* la = hL + par * (BATCH * HDIM) + (m0 + lr) * HDIM;
    const float* hc = hf + par * (BATCH * HDIM);

    // ---- stage 1: r,z pre-activations (64 x 32 slice, K=1024, 3-term bf16) ----
    f32x4 accR0 = (f32x4){0,0,0,0}, accR1 = (f32x4){0,0,0,0};
    f32x4 accZ0 = (f32x4){0,0,0,0}, accZ1 = (f32x4){0,0,0,0};
    #pragma unroll 4
    for (int k0 = 0; k0 < HDIM; k0 += 32) {
      int ka = k0 + lk;
      sh8 aH = *(const sh8*)(ha + ka);
      sh8 aL = *(const sh8*)(la + ka);
      sh8 rH = *(const sh8*)(wrH + ka);
      sh8 rL = *(const sh8*)(wrL + ka);
      sh8 zH = *(const sh8*)(wzH + ka);
      sh8 zL = *(const sh8*)(wzL + ka);
      if ((k0 >> 5) & 1) {
        accR1 = MFMA16(aH, rH, accR1); accR1 = MFMA16(aH, rL, accR1); accR1 = MFMA16(aL, rH, accR1);
        accZ1 = MFMA16(aH, zH, accZ1); accZ1 = MFMA16(aH, zL, accZ1); accZ1 = MFMA16(aL, zH, accZ1);
      } else {
        accR0 = MFMA16(aH, rH, accR0); accR0 = MFMA16(aH, rL, accR0); accR0 = MFMA16(aL, rH, accR0);
        accZ0 = MFMA16(aH, zH, accZ0); accZ0 = MFMA16(aH, zL, accZ0); accZ0 = MFMA16(aL, zH, accZ0);
      }
    }
    f32x4 accR = accR0 + accR1;
    f32x4 accZ = accZ0 + accZ1;

    float zreg[4];
    const float* gxt = gx + (size_t)t * (BATCH * G3);
    #pragma unroll
    for (int j = 0; j < 4; ++j) {
      int b = m0 + rb + j, c = c0 + lr;
      float pr = accR[j] + gxt[b * G3 + c] + bias_hh[c];
      float pz = accZ[j] + gxt[b * G3 + 1024 + c] + bias_hh[1024 + c];
      float r = 1.f / (1.f + __expf(-pr));
      float z = 1.f / (1.f + __expf(-pz));
      zreg[j] = z;
      float rhv = r * hc[b * HDIM + c];
      ushort_t hi = f2bf(rhv);
      rhH[b * HDIM + c] = hi;
      rhL[b * HDIM + c] = f2bf(rhv - bf2f(hi));
    }
    gbar(cnt, ++bar * 64);

    // ---- stage 2: n pre-activation (64 x 16 slice, K=1024 over r*h) ----
    f32x4 accN0 = (f32x4){0,0,0,0}, accN1 = (f32x4){0,0,0,0};
    const ushort_t* ra = rhH + (m0 + lr) * HDIM;
    const ushort_t* rl = rhL + (m0 + lr) * HDIM;
    #pragma unroll 4
    for (int k0 = 0; k0 < HDIM; k0 += 32) {
      int ka = k0 + lk;
      sh8 aH = *(const sh8*)(ra + ka);
      sh8 aL = *(const sh8*)(rl + ka);
      sh8 nH = *(const sh8*)(wnH + ka);
      sh8 nL = *(const sh8*)(wnL + ka);
      if ((k0 >> 5) & 1) {
        accN1 = MFMA16(aH, nH, accN1); accN1 = MFMA16(aH, nL, accN1); accN1 = MFMA16(aL, nH, accN1);
      } else {
        accN0 = MFMA16(aH, nH, accN0); accN0 = MFMA16(aH, nL, accN0); accN0 = MFMA16(aL, nH, accN0);
      }
    }
    f32x4 accN = accN0 + accN1;

    float* hfn = hf + (par ^ 1) * (BATCH * HDIM);
    ushort_t* hHn = hH + (par ^ 1) * (BATCH * HDIM);
    ushort_t* hLn = hL + (par ^ 1) * (BATCH * HDIM);
    #pragma unroll
    for (int j = 0; j < 4; ++j) {
      int b = m0 + rb + j, c = c0 + lr;
      float pn = accN[j] + gxt[b * G3 + 2048 + c] + bias_hh[2048 + c];
      float n = tanhf(pn);
      float hold = hc[b * HDIM + c];
      float z = zreg[j];
      float hnew = (1.f - z) * n + z * hold;
      Y[(size_t)t * (BATCH * HDIM) + b * HDIM + c] = hnew;
      hfn[b * HDIM + c] = hnew;
      ushort_t hi = f2bf(hnew);
      hHn[b * HDIM + c] = hi;
      hLn[b * HDIM + c] = f2bf(hnew - bf2f(hi));
      if (t == SEQL - 1) Yh[b * HDIM + c] = hnew;
    }
    gbar(cnt, ++bar * 64);
  }
}

// ---------------- launch ----------------
extern "C" void kernel_launch(void* const* d_in, const int* in_sizes, int n_in,
                              void* d_out, int out_size, void* d_ws, size_t ws_size,
                              hipStream_t stream) {
  const float* input = (const float*)d_in[0];
  const float* h0    = (const float*)d_in[1];
  const float* wih   = (const float*)d_in[2];
  const float* whh   = (const float*)d_in[3];
  const float* bih   = (const float*)d_in[4];
  const float* bhh   = (const float*)d_in[5];

  char* ws = (char*)d_ws;
  size_t o = 0;
  float* gx = (float*)(ws + o);        o += (size_t)AROWS * G3 * 4;        // 402,653,184
  ushort_t* WihH = (ushort_t*)(ws + o); o += (size_t)G3 * HDIM * 2;
  ushort_t* WihL = (ushort_t*)(ws + o); o += (size_t)G3 * HDIM * 2;
  ushort_t* WhhH = (ushort_t*)(ws + o); o += (size_t)G3 * HDIM * 2;
  ushort_t* WhhL = (ushort_t*)(ws + o); o += (size_t)G3 * HDIM * 2;
  float* hf = (float*)(ws + o);         o += 2 * (size_t)BATCH * HDIM * 4;
  ushort_t* hH = (ushort_t*)(ws + o);   o += 2 * (size_t)BATCH * HDIM * 2;
  ushort_t* hL = (ushort_t*)(ws + o);   o += 2 * (size_t)BATCH * HDIM * 2;
  ushort_t* rhH = (ushort_t*)(ws + o);  o += (size_t)BATCH * HDIM * 2;
  ushort_t* rhL = (ushort_t*)(ws + o);  o += (size_t)BATCH * HDIM * 2;
  unsigned* cnt = (unsigned*)(ws + o);  o += 256;

  float* Y  = (float*)d_out;
  float* Yh = (float*)d_out + (size_t)YSZ;

  hipMemsetAsync(cnt, 0, 256, stream);
  cvt_kernel<<<2048, 256, 0, stream>>>(wih, whh, h0, WihH, WihL, WhhH, WhhL, hf, hH, hL);
  gemm_gx<<<(AROWS / 128) * (G3 / 128), 256, 0, stream>>>(input, WihH, WihL, bih, gx);
  gru_rec<<<64, 256, 0, stream>>>(gx, WhhH, WhhL, bhh, hf, hH, hL, rhH, rhL, Y, Yh, cnt);
}

// Round 2
// 16131.627 us; speedup vs baseline: 1.9724x; 1.9724x over previous
//
#include <hip/hip_runtime.h>

typedef unsigned short ushort_t;
typedef short sh8 __attribute__((ext_vector_type(8)));     // 8 bf16 (4 VGPR)
typedef float f32x4 __attribute__((ext_vector_type(4)));   // 4 fp32 acc

#define MFMA16(a,b,c) __builtin_amdgcn_mfma_f32_16x16x32_bf16((a),(b),(c),0,0,0)

#define SEQL   512
#define BATCH  64
#define HDIM   1024
#define G3     3072
#define AROWS  (SEQL*BATCH)          // 32768
#define YSZ    (SEQL*BATCH*HDIM)     // 33554432
#define BH     (BATCH*HDIM)          // 65536

__device__ __forceinline__ ushort_t f2bf(float x) {
  unsigned u = __float_as_uint(x);
  u += 0x7FFFu + ((u >> 16) & 1u);    // RNE
  return (ushort_t)(u >> 16);
}
__device__ __forceinline__ float bf2f(ushort_t h) {
  return __uint_as_float(((unsigned)h) << 16);
}

// ---------------- conversion / init ----------------
__global__ void cvt_kernel(const float* __restrict__ wih, const float* __restrict__ whh,
                           const float* __restrict__ h0,
                           ushort_t* __restrict__ WihH, ushort_t* __restrict__ WihL,
                           ushort_t* __restrict__ WhhH, ushort_t* __restrict__ WhhL,
                           ushort_t* __restrict__ hH, ushort_t* __restrict__ hL) {
  const int NW = G3 * HDIM;
  int i0 = blockIdx.x * blockDim.x + threadIdx.x;
  int stride = gridDim.x * blockDim.x;
  for (int i = i0; i < NW; i += stride) {
    float x = wih[i]; ushort_t h = f2bf(x);
    WihH[i] = h; WihL[i] = f2bf(x - bf2f(h));
    float y = whh[i]; ushort_t g = f2bf(y);
    WhhH[i] = g; WhhL[i] = f2bf(y - bf2f(g));
  }
  for (int i = i0; i < BH; i += stride) {
    float x = h0[i];
    ushort_t h = f2bf(x); hH[i] = h; hL[i] = f2bf(x - bf2f(h));
  }
}

// ---------------- phase 1: gx = input @ W_ih^T + b_ih (3-term bf16) ----------------
__global__ __launch_bounds__(256) void gemm_gx(
    const float* __restrict__ A,            // [32768][1024] fp32
    const ushort_t* __restrict__ BHp, const ushort_t* __restrict__ BLp, // [3072][1024]
    const float* __restrict__ bias,         // [3072]
    float* __restrict__ gx)                 // [32768][3072]
{
  int bid = blockIdx.x;
  int mt = bid / 24, nt = bid % 24;
  int w = threadIdx.x >> 6, l = threadIdx.x & 63;
  int lr = l & 15, lk = (l >> 4) * 8;

  f32x4 acc[2][8];
  #pragma unroll
  for (int mi = 0; mi < 2; ++mi)
    #pragma unroll
    for (int ni = 0; ni < 8; ++ni) acc[mi][ni] = (f32x4){0.f, 0.f, 0.f, 0.f};

  int arow0 = mt * 128 + w * 32 + lr;
  int brow0 = nt * 128 + lr;

  for (int k0 = 0; k0 < HDIM; k0 += 32) {
    int ka = k0 + lk;
    sh8 aH[2], aL[2];
    #pragma unroll
    for (int mi = 0; mi < 2; ++mi) {
      const float* ap = A + (size_t)(arow0 + mi * 16) * HDIM + ka;
      float4 x0 = *(const float4*)ap;
      float4 x1 = *(const float4*)(ap + 4);
      float xs[8] = {x0.x, x0.y, x0.z, x0.w, x1.x, x1.y, x1.z, x1.w};
      #pragma unroll
      for (int j = 0; j < 8; ++j) {
        ushort_t h = f2bf(xs[j]);
        aH[mi][j] = (short)h;
        aL[mi][j] = (short)f2bf(xs[j] - bf2f(h));
      }
    }
    #pragma unroll
    for (int ni = 0; ni < 8; ++ni) {
      const ushort_t* bh = BHp + (size_t)(brow0 + ni * 16) * HDIM + ka;
      const ushort_t* bl = BLp + (size_t)(brow0 + ni * 16) * HDIM + ka;
      sh8 bHf = *(const sh8*)bh;
      sh8 bLf = *(const sh8*)bl;
      #pragma unroll
      for (int mi = 0; mi < 2; ++mi) {
        acc[mi][ni] = MFMA16(aH[mi], bHf, acc[mi][ni]);
        acc[mi][ni] = MFMA16(aH[mi], bLf, acc[mi][ni]);
        acc[mi][ni] = MFMA16(aL[mi], bHf, acc[mi][ni]);
      }
    }
  }
  int rb = (l >> 4) * 4;
  #pragma unroll
  for (int mi = 0; mi < 2; ++mi)
    #pragma unroll
    for (int ni = 0; ni < 8; ++ni) {
      int col = nt * 128 + ni * 16 + lr;
      float b = bias[col];
      #pragma unroll
      for (int j = 0; j < 4; ++j) {
        int row = mt * 128 + w * 32 + mi * 16 + rb + j;
        gx[(size_t)row * G3 + col] = acc[mi][ni][j] + b;
      }
    }
}

// ---------------- device-scope barrier ----------------
__device__ __forceinline__ void gbar(unsigned* cnt, unsigned target) {
  __syncthreads();
  if (threadIdx.x == 0) {
    __hip_atomic_fetch_add(cnt, 1u, __ATOMIC_RELEASE, __HIP_MEMORY_SCOPE_AGENT);
    while (__hip_atomic_load(cnt, __ATOMIC_ACQUIRE, __HIP_MEMORY_SCOPE_AGENT) < target)
      __builtin_amdgcn_s_sleep(1);
  }
  __syncthreads();
}

// ---------------- phase 2: persistent recurrence ----------------
// 64 WGs x 256 threads. WG g owns hidden cols [16g,16g+16). Wave w owns rows [16w,16w+16).
// W_hh slices live in LDS (128KB): rH@0, zH@32K, nH@64K, nL@96K, XOR-swizzled.
__global__ __launch_bounds__(256, 1) void gru_rec(
    const float* __restrict__ gx,                 // [512][64][3072]
    const ushort_t* __restrict__ WhhH, const ushort_t* __restrict__ WhhL, // [3072][1024]
    const float* __restrict__ bias_hh,            // [3072]
    ushort_t* __restrict__ hH, ushort_t* __restrict__ hL,   // [2][64][1024]
    ushort_t* __restrict__ rhH, ushort_t* __restrict__ rhL, // [64][1024]
    float* __restrict__ Y, float* __restrict__ Yh,
    unsigned* __restrict__ cnt)
{
  extern __shared__ char lds[];
  const int g = blockIdx.x;
  const int w = threadIdx.x >> 6, l = threadIdx.x & 63;
  const int lr = l & 15, lk = (l >> 4) * 8, rb = (l >> 4) * 4;
  const int c0 = g * 16, m0 = w * 16;
  const int c = c0 + lr;

  // ---- one-time LDS fill: 64 rows x 2KB, swizzled byte ^= (row&7)<<4 ----
  #pragma unroll
  for (int p = 0; p < 32; ++p) {
    int q = threadIdx.x + p * 256;
    int flat = q * 16;
    int lrow = flat >> 11;
    int off = flat & 2047;
    int dst = flat ^ ((lrow & 7) << 4);
    const ushort_t* src;
    if (lrow < 16)      src = WhhH + (size_t)(c0 + lrow) * HDIM;
    else if (lrow < 32) src = WhhH + (size_t)(1024 + c0 + lrow - 16) * HDIM;
    else if (lrow < 48) src = WhhH + (size_t)(2048 + c0 + lrow - 32) * HDIM;
    else                src = WhhL + (size_t)(2048 + c0 + lrow - 48) * HDIM;
    *(sh8*)(lds + dst) = *(const sh8*)(src + (off >> 1));
  }
  __syncthreads();

  const float br = bias_hh[c], bz = bias_hh[1024 + c], bn = bias_hh[2048 + c];
  unsigned bar = 0;

  for (int t = 0; t < SEQL; ++t) {
    const int par = t & 1;
    const float* gxt = gx + (size_t)t * (BATCH * G3);

    // ---- stage 1: prefetch gx + own-h, preload A (h hi/lo) across full K ----
    float gxr[4], gxz[4], gxn[4];
    ushort_t uh[4], ul[4];
    #pragma unroll
    for (int j = 0; j < 4; ++j) {
      int b = m0 + rb + j;
      gxr[j] = gxt[(size_t)b * G3 + c];
      gxz[j] = gxt[(size_t)b * G3 + 1024 + c];
      gxn[j] = gxt[(size_t)b * G3 + 2048 + c];
      uh[j] = hH[par * BH + b * HDIM + c];
      ul[j] = hL[par * BH + b * HDIM + c];
    }
    const ushort_t* ha = hH + par * BH + (size_t)(m0 + lr) * HDIM + lk;
    const ushort_t* la = hL + par * BH + (size_t)(m0 + lr) * HDIM + lk;
    sh8 aH[32], aL[32];
    #pragma unroll
    for (int i = 0; i < 32; ++i) {
      aH[i] = *(const sh8*)(ha + i * 32);
      aL[i] = *(const sh8*)(la + i * 32);
    }

    f32x4 accR = (f32x4){0,0,0,0}, accZ = (f32x4){0,0,0,0};
    #pragma unroll
    for (int i = 0; i < 32; ++i) {
      int byt = (lr << 11) + ((i * 32 + lk) << 1);
      byt ^= (lr & 7) << 4;
      sh8 rW = *(const sh8*)(lds + byt);
      sh8 zW = *(const sh8*)(lds + 32768 + byt);
      accR = MFMA16(aH[i], rW, accR);
      accR = MFMA16(aL[i], rW, accR);
      accZ = MFMA16(aH[i], zW, accZ);
      accZ = MFMA16(aL[i], zW, accZ);
    }

    float zreg[4], hold[4];
    #pragma unroll
    for (int j = 0; j < 4; ++j) {
      int b = m0 + rb + j;
      hold[j] = bf2f(uh[j]) + bf2f(ul[j]);
      float pr = accR[j] + gxr[j] + br;
      float pz = accZ[j] + gxz[j] + bz;
      float r = 1.f / (1.f + __expf(-pr));
      zreg[j] = 1.f / (1.f + __expf(-pz));
      float rhv = r * hold[j];
      ushort_t hi = f2bf(rhv);
      rhH[b * HDIM + c] = hi;
      rhL[b * HDIM + c] = f2bf(rhv - bf2f(hi));
    }
    gbar(cnt, ++bar * 64);

    // ---- stage 2: n gate (3-term over rh), then h update ----
    const ushort_t* ra = rhH + (size_t)(m0 + lr) * HDIM + lk;
    const ushort_t* rl = rhL + (size_t)(m0 + lr) * HDIM + lk;
    sh8 pH[32], pL[32];
    #pragma unroll
    for (int i = 0; i < 32; ++i) {
      pH[i] = *(const sh8*)(ra + i * 32);
      pL[i] = *(const sh8*)(rl + i * 32);
    }
    f32x4 accN = (f32x4){0,0,0,0};
    #pragma unroll
    for (int i = 0; i < 32; ++i) {
      int byt = (lr << 11) + ((i * 32 + lk) << 1);
      byt ^= (lr & 7) << 4;
      sh8 nW = *(const sh8*)(lds + 65536 + byt);
      sh8 nLo = *(const sh8*)(lds + 98304 + byt);
      accN = MFMA16(pH[i], nW, accN);
      accN = MFMA16(pH[i], nLo, accN);
      accN = MFMA16(pL[i], nW, accN);
    }

    ushort_t* hHn = hH + (par ^ 1) * BH;
    ushort_t* hLn = hL + (par ^ 1) * BH;
    #pragma unroll
    for (int j = 0; j < 4; ++j) {
      int b = m0 + rb + j;
      float pn = accN[j] + gxn[j] + bn;
      float n = tanhf(pn);
      float z = zreg[j];
      float hnew = (1.f - z) * n + z * hold[j];
      Y[(size_t)t * BH + b * HDIM + c] = hnew;
      ushort_t hi = f2bf(hnew);
      hHn[b * HDIM + c] = hi;
      hLn[b * HDIM + c] = f2bf(hnew - bf2f(hi));
      if (t == SEQL - 1) Yh[b * HDIM + c] = hnew;
    }
    gbar(cnt, ++bar * 64);
  }
}

// ---------------- launch ----------------
extern "C" void kernel_launch(void* const* d_in, const int* in_sizes, int n_in,
                              void* d_out, int out_size, void* d_ws, size_t ws_size,
                              hipStream_t stream) {
  const float* input = (const float*)d_in[0];
  const float* h0    = (const float*)d_in[1];
  const float* wih   = (const float*)d_in[2];
  const float* whh   = (const float*)d_in[3];
  const float* bih   = (const float*)d_in[4];
  const float* bhh   = (const float*)d_in[5];

  char* ws = (char*)d_ws;
  size_t o = 0;
  float* gx = (float*)(ws + o);         o += (size_t)AROWS * G3 * 4;
  ushort_t* WihH = (ushort_t*)(ws + o); o += (size_t)G3 * HDIM * 2;
  ushort_t* WihL = (ushort_t*)(ws + o); o += (size_t)G3 * HDIM * 2;
  ushort_t* WhhH = (ushort_t*)(ws + o); o += (size_t)G3 * HDIM * 2;
  ushort_t* WhhL = (ushort_t*)(ws + o); o += (size_t)G3 * HDIM * 2;
  ushort_t* hH = (ushort_t*)(ws + o);   o += 2 * (size_t)BH * 2;
  ushort_t* hL = (ushort_t*)(ws + o);   o += 2 * (size_t)BH * 2;
  ushort_t* rhH = (ushort_t*)(ws + o);  o += (size_t)BH * 2;
  ushort_t* rhL = (ushort_t*)(ws + o);  o += (size_t)BH * 2;
  unsigned* cnt = (unsigned*)(ws + o);  o += 256;

  float* Y  = (float*)d_out;
  float* Yh = (float*)d_out + (size_t)YSZ;

  hipFuncSetAttribute((const void*)gru_rec,
                      hipFuncAttributeMaxDynamicSharedMemorySize, 131072);

  hipMemsetAsync(cnt, 0, 256, stream);
  cvt_kernel<<<2048, 256, 0, stream>>>(wih, whh, h0, WihH, WihL, WhhH, WhhL, hH, hL);
  gemm_gx<<<(AROWS / 128) * (G3 / 128), 256, 0, stream>>>(input, WihH, WihL, bih, gx);
  gru_rec<<<64, 256, 131072, stream>>>(gx, WhhH, WhhL, bhh, hH, hL, rhH, rhL, Y, Yh, cnt);
}